// Round 8
// baseline (780.679 us; speedup 1.0000x reference)
//
#include <hip/hip_runtime.h>
#include <hip/hip_bf16.h>
#include <math.h>

#define BB   2
#define SS   2048
#define DIM  1024
#define NH   16
#define HD   64
#define MTOT (BB * SS)   // 4096

typedef unsigned short ushortT;
typedef __attribute__((ext_vector_type(8))) short short8v;   // 8 bf16 (4 VGPRs)
typedef __attribute__((ext_vector_type(4))) float float4v;   // 4 fp32 acc

union FragU { short8v v; unsigned short us[8]; unsigned int u[4]; };

__device__ inline unsigned short f2bf(float x) {             // fp32 -> bf16 RNE
    unsigned u = __builtin_bit_cast(unsigned, x);
    u += 0x7fffu + ((u >> 16) & 1u);
    return (unsigned short)(u >> 16);
}
__device__ inline float bf2f(unsigned short h) {
    unsigned u = ((unsigned)h) << 16;
    return __builtin_bit_cast(float, u);
}
// truncation split: hi = trunc-to-bf16(x), lo = trunc-to-bf16(x - hi)
__device__ inline void split_tr(float x, unsigned short& hi, unsigned short& lo) {
    unsigned u = __builtin_bit_cast(unsigned, x);
    hi = (unsigned short)(u >> 16);
    float hf = __builtin_bit_cast(float, u & 0xffff0000u);
    lo = (unsigned short)(__builtin_bit_cast(unsigned, x - hf) >> 16);
}
__device__ inline void split4(const float4& x, short4& hi, short4& lo) {
    unsigned short h0 = f2bf(x.x), h1 = f2bf(x.y), h2 = f2bf(x.z), h3 = f2bf(x.w);
    hi = make_short4((short)h0, (short)h1, (short)h2, (short)h3);
    lo = make_short4((short)f2bf(x.x - bf2f(h0)), (short)f2bf(x.y - bf2f(h1)),
                     (short)f2bf(x.z - bf2f(h2)), (short)f2bf(x.w - bf2f(h3)));
}
// async global->LDS, 16 B per lane (dest = wave-uniform base + lane*16)
__device__ inline void gld_lds16(const void* g, void* l) {
    __builtin_amdgcn_global_load_lds(
        (const __attribute__((address_space(1))) void*)g,
        (__attribute__((address_space(3))) void*)l, 16, 0, 0);
}

// ---------------------------------------------------------------------------
// prep: z<4 -> W[z] transpose+split into WtH/WtL; z>=4 -> X elementwise split.
// grid (16,16,20), 256 threads.
// ---------------------------------------------------------------------------
__global__ __launch_bounds__(256) void prep_kernel(
    const float* __restrict__ x,
    const float* __restrict__ W0, const float* __restrict__ W1,
    const float* __restrict__ W2, const float* __restrict__ W3,
    ushortT* __restrict__ XhS, ushortT* __restrict__ XlS,
    ushortT* __restrict__ WtH, ushortT* __restrict__ WtL)
{
    const int z = blockIdx.z;
    const int tid = threadIdx.x;
    if (z >= 4) {
        // X split: 1M float4 groups
        int t = (((z - 4) * 256 + blockIdx.y * 16 + blockIdx.x)) * 256 + tid;
        float4 xv = ((const float4*)x)[t];
        short4 h, l; split4(xv, h, l);
        ((short4*)XhS)[t] = h;
        ((short4*)XlS)[t] = l;
        return;
    }
    const float* __restrict__ W = (z == 0) ? W0 : (z == 1) ? W1 : (z == 2) ? W2 : W3;
    ushortT* H = WtH + (size_t)z * 1024 * 1024;
    ushortT* L = WtL + (size_t)z * 1024 * 1024;

    __shared__ float T[64][65];
    const int k0 = blockIdx.y * 64, n0 = blockIdx.x * 64;
    const int c4 = (tid & 15) * 4;

#pragma unroll
    for (int i = 0; i < 4; i++) {
        int r = (tid >> 4) + 16 * i;
        *(float4*)&T[r][c4] = *(const float4*)(W + (size_t)(k0 + r) * 1024 + n0 + c4);
    }
    __syncthreads();
#pragma unroll
    for (int i = 0; i < 4; i++) {
        int n = (tid >> 4) + 16 * i;
        float4 vv = make_float4(T[c4 + 0][n], T[c4 + 1][n], T[c4 + 2][n], T[c4 + 3][n]);
        short4 h, l; split4(vv, h, l);
        *(short4*)&H[(size_t)(n0 + n) * 1024 + k0 + c4] = h;
        *(short4*)&L[(size_t)(n0 + n) * 1024 + k0 + c4] = l;
    }
}

// ---------------------------------------------------------------------------
// Split-bf16 MFMA GEMM.
//   z==0: Q projection, fp32 rows -> Y0.
//   z==1: K projection, operand-SWAPPED mfma (tokens on lanes, d on regs) ->
//         direct frag-major split-bf16 K tiles (r-consecutive b64 stores).
//   z==2: V projection -> direct frag-major split-bf16 V tiles (round-7 path).
// ---------------------------------------------------------------------------
__global__ __launch_bounds__(256, 3) void gemm_bt_split_kernel(
    const ushortT* __restrict__ Ah, const ushortT* __restrict__ Al,
    const ushortT* __restrict__ BtH, const ushortT* __restrict__ BtL,
    float* __restrict__ Y0,
    ushortT* __restrict__ KhG, ushortT* __restrict__ KlG,
    ushortT* __restrict__ VhG, ushortT* __restrict__ VlG)
{
    const int z = blockIdx.z;
    const ushortT* __restrict__ Bh = BtH + (size_t)z * 1024 * 1024;
    const ushortT* __restrict__ Bl = BtL + (size_t)z * 1024 * 1024;

    const int K = 1024, N = 1024;
    const int m0 = blockIdx.y * 128;
    const int n0 = blockIdx.x * 128;

    __shared__ __align__(16) ushortT AhS[128 * 32];
    __shared__ __align__(16) ushortT AlS[128 * 32];
    __shared__ __align__(16) ushortT BhS[128 * 32];
    __shared__ __align__(16) ushortT BlS[128 * 32];

    const int tid  = threadIdx.x;
    const int wave = tid >> 6, lane = tid & 63;
    const int quad = lane >> 4, l15 = lane & 15;
    const int wm = wave >> 1, wn = wave & 1;

    const int s0 = tid, s1 = tid + 256;
    const int ar0 = s0 >> 2, ak0 = (s0 & 3) * 8;
    const int ar1 = s1 >> 2, ak1 = (s1 & 3) * 8;

    float4v acc[4][4];
#pragma unroll
    for (int i = 0; i < 4; i++)
#pragma unroll
        for (int j = 0; j < 4; j++) acc[i][j] = (float4v){0.f, 0.f, 0.f, 0.f};

    for (int k0 = 0; k0 < K; k0 += 32) {
        __syncthreads();
        gld_lds16(Ah + (size_t)(m0 + ar0) * K + k0 + ak0, &AhS[s0 * 8]);
        gld_lds16(Ah + (size_t)(m0 + ar1) * K + k0 + ak1, &AhS[s1 * 8]);
        gld_lds16(Al + (size_t)(m0 + ar0) * K + k0 + ak0, &AlS[s0 * 8]);
        gld_lds16(Al + (size_t)(m0 + ar1) * K + k0 + ak1, &AlS[s1 * 8]);
        gld_lds16(Bh + (size_t)(n0 + ar0) * K + k0 + ak0, &BhS[s0 * 8]);
        gld_lds16(Bh + (size_t)(n0 + ar1) * K + k0 + ak1, &BhS[s1 * 8]);
        gld_lds16(Bl + (size_t)(n0 + ar0) * K + k0 + ak0, &BlS[s0 * 8]);
        gld_lds16(Bl + (size_t)(n0 + ar1) * K + k0 + ak1, &BlS[s1 * 8]);
        __syncthreads();

        FragU ah[4], al[4], bh[4], bl[4];
#pragma unroll
        for (int t = 0; t < 4; t++) {
            ah[t].v = *(const short8v*)&AhS[(wm * 64 + t * 16 + l15) * 32 + quad * 8];
            al[t].v = *(const short8v*)&AlS[(wm * 64 + t * 16 + l15) * 32 + quad * 8];
            bh[t].v = *(const short8v*)&BhS[(wn * 64 + t * 16 + l15) * 32 + quad * 8];
            bl[t].v = *(const short8v*)&BlS[(wn * 64 + t * 16 + l15) * 32 + quad * 8];
        }
        if (z == 1) {
            // swapped operands: acc[mt][nt] = C'[m=d][n=token]
#pragma unroll
            for (int mt = 0; mt < 4; mt++)
#pragma unroll
                for (int nt = 0; nt < 4; nt++) {
                    acc[mt][nt] = __builtin_amdgcn_mfma_f32_16x16x32_bf16(bh[nt].v, ah[mt].v, acc[mt][nt], 0, 0, 0);
                    acc[mt][nt] = __builtin_amdgcn_mfma_f32_16x16x32_bf16(bh[nt].v, al[mt].v, acc[mt][nt], 0, 0, 0);
                    acc[mt][nt] = __builtin_amdgcn_mfma_f32_16x16x32_bf16(bl[nt].v, ah[mt].v, acc[mt][nt], 0, 0, 0);
                }
        } else {
#pragma unroll
            for (int mt = 0; mt < 4; mt++)
#pragma unroll
                for (int nt = 0; nt < 4; nt++) {
                    acc[mt][nt] = __builtin_amdgcn_mfma_f32_16x16x32_bf16(ah[mt].v, bh[nt].v, acc[mt][nt], 0, 0, 0);
                    acc[mt][nt] = __builtin_amdgcn_mfma_f32_16x16x32_bf16(ah[mt].v, bl[nt].v, acc[mt][nt], 0, 0, 0);
                    acc[mt][nt] = __builtin_amdgcn_mfma_f32_16x16x32_bf16(al[mt].v, bh[nt].v, acc[mt][nt], 0, 0, 0);
                }
        }
    }

    if (z == 1) {
        // K epilogue: token = m0+wm*64+mt*16+l15 ; d = n0+wn*64+nt*16+quad*4+r
        const int b  = m0 >> 11;
        const int jb = ((m0 & 2047) >> 6) + wm;
        const int h  = (n0 >> 6) + wn;
        const size_t tb = (size_t)((b * 16 + h) * 32 + jb) * 4096;
        ushortT* kh = KhG + tb;
        ushortT* kl = KlG + tb;
#pragma unroll
        for (int mt = 0; mt < 4; mt++)
#pragma unroll
            for (int nt = 0; nt < 4; nt++) {
                const int off = (((nt >> 1) * 4 + mt) * 64 +
                                 (((2 * nt + (quad >> 1)) & 3) * 16 + l15)) * 8 +
                                (quad & 1) * 4;
                unsigned short h0, l0, h1, l1, h2, l2, h3, l3;
                split_tr(acc[mt][nt][0], h0, l0); split_tr(acc[mt][nt][1], h1, l1);
                split_tr(acc[mt][nt][2], h2, l2); split_tr(acc[mt][nt][3], h3, l3);
                *(short4*)&kh[off] = make_short4((short)h0, (short)h1, (short)h2, (short)h3);
                *(short4*)&kl[off] = make_short4((short)l0, (short)l1, (short)l2, (short)l3);
            }
    } else if (z == 2) {
        // V epilogue (round-7): frag f=(mt>>1)*4+nt, lane=((mt&1)*2+(quad>>1))*16+l15
        const int b  = m0 >> 11;
        const int jb = ((m0 & 2047) >> 6) + wm;
        const int h  = (n0 >> 6) + wn;
        const size_t tb = (size_t)((b * 16 + h) * 32 + jb) * 4096;
        ushortT* vh = VhG + tb;
        ushortT* vl = VlG + tb;
#pragma unroll
        for (int mt = 0; mt < 4; mt++)
#pragma unroll
            for (int nt = 0; nt < 4; nt++) {
                const int off = ((((mt >> 1) * 4 + nt) * 64 +
                                  ((mt & 1) * 2 + (quad >> 1)) * 16 + l15) * 8) +
                                (quad & 1) * 4;
                unsigned short h0, l0, h1, l1, h2, l2, h3, l3;
                split_tr(acc[mt][nt][0], h0, l0); split_tr(acc[mt][nt][1], h1, l1);
                split_tr(acc[mt][nt][2], h2, l2); split_tr(acc[mt][nt][3], h3, l3);
                *(short4*)&vh[off] = make_short4((short)h0, (short)h1, (short)h2, (short)h3);
                *(short4*)&vl[off] = make_short4((short)l0, (short)l1, (short)l2, (short)l3);
            }
    } else {
#pragma unroll
        for (int mt = 0; mt < 4; mt++)
#pragma unroll
            for (int r = 0; r < 4; r++) {
                const int row = m0 + wm * 64 + mt * 16 + quad * 4 + r;
                float* yp = Y0 + (size_t)row * N + n0 + wn * 64 + l15;
#pragma unroll
                for (int nt = 0; nt < 4; nt++)
                    yp[nt * 16] = acc[mt][nt][r];
            }
    }
}

// ---------------------------------------------------------------------------
// MFMA attention v6: pipelined staging. K frags read to regs at iter top ->
// barrier -> issue NEXT iter's K gld (issue distance = S+stats+P phase);
// V frags read mid-body -> barrier -> issue next V gld (distance = PV phase).
// Every vmcnt drain has >1000 cycles of covered latency. Math identical to
// round-5/7: S^T = K·Q^T, exp2 softmax, per-step division folded as
// O = (alpha*inv)*O + (P*inv)@V  ==  (alpha*O + P@V)/l_new.
// ---------------------------------------------------------------------------
__global__ __launch_bounds__(256, 2) void attn_mfma_kernel(
    const float* __restrict__ q,
    const ushortT* __restrict__ KhG, const ushortT* __restrict__ KlG,
    const ushortT* __restrict__ VhG, const ushortT* __restrict__ VlG,
    ushortT* __restrict__ Oh, ushortT* __restrict__ Ol)
{
    __shared__ __align__(16) ushortT KhS[4096];
    __shared__ __align__(16) ushortT KlS[4096];
    __shared__ __align__(16) ushortT VhS[4096];
    __shared__ __align__(16) ushortT VlS[4096];
    __shared__ __align__(16) ushortT PW[4][2][2048];   // [wave][hi/lo][frag4*slot64*j8]

    const int tid  = threadIdx.x;
    const int wave = tid >> 6, lane = tid & 63;
    const int quad = lane >> 4, l15 = lane & 15;
    const int bh = blockIdx.y, b = bh >> 4, h = bh & 15;
    const size_t base = (size_t)b * SS * DIM + (size_t)h * HD;
    const int qs0 = blockIdx.x * 128 + wave * 32;

    // ---- Q fragments: scale = 1/8 * log2(e) folded in (exp2 domain) ----
    const float qscale = 0.125f * 1.4426950408889634f;
    FragU Qh[2][2], Ql[2][2];
#pragma unroll
    for (int rt = 0; rt < 2; rt++) {
        const int qrow = qs0 + rt * 16 + l15;
#pragma unroll
        for (int ks = 0; ks < 2; ks++) {
            const float* p0 = q + base + (size_t)qrow * DIM + ks * 32 + quad * 8;
            float4 a = *(const float4*)(p0);
            float4 c = *(const float4*)(p0 + 4);
            float e[8] = {a.x, a.y, a.z, a.w, c.x, c.y, c.z, c.w};
#pragma unroll
            for (int j = 0; j < 8; j++) {
                float xj = e[j] * qscale;
                unsigned short hs = f2bf(xj);
                Qh[rt][ks].us[j] = hs;
                Ql[rt][ks].us[j] = f2bf(xj - bf2f(hs));
            }
        }
    }

    float4v Oacc[4][2];   // [dt][rt], O^T: row d=dt*16+quad*4+r, col q=rt*16+l15
#pragma unroll
    for (int dt = 0; dt < 4; dt++)
#pragma unroll
        for (int rt = 0; rt < 2; rt++) Oacc[dt][rt] = (float4v){0.f, 0.f, 0.f, 0.f};

    float m_run[2] = {-INFINITY, -INFINITY};
    float l_run[2] = {0.f, 0.f};

    const int sl0 = wave * 128 + lane, sl1 = sl0 + 64;
    ushortT* ph = &PW[wave][0][0];
    ushortT* pl = &PW[wave][1][0];
    const int pwq = ((quad >> 1) * 16 + l15) * 8 + (quad & 1) * 4;
    const int lane8 = lane * 8;

    // ---- prologue: stage tile 0 (K and V) ----
    {
        const size_t tb = (size_t)(bh * 32) * 4096;
        gld_lds16(KhG + tb + sl0 * 8, &KhS[sl0 * 8]);
        gld_lds16(KhG + tb + sl1 * 8, &KhS[sl1 * 8]);
        gld_lds16(KlG + tb + sl0 * 8, &KlS[sl0 * 8]);
        gld_lds16(KlG + tb + sl1 * 8, &KlS[sl1 * 8]);
        gld_lds16(VhG + tb + sl0 * 8, &VhS[sl0 * 8]);
        gld_lds16(VhG + tb + sl1 * 8, &VhS[sl1 * 8]);
        gld_lds16(VlG + tb + sl0 * 8, &VlS[sl0 * 8]);
        gld_lds16(VlG + tb + sl1 * 8, &VlS[sl1 * 8]);
    }

    for (int jb = 0; jb < 32; jb++) {
        const size_t tbn = (size_t)(bh * 32 + jb + 1) * 4096;   // next tile
        __syncthreads();   // tile jb fully staged (drains pipelined gld)

        // ---- K frags -> regs ----
        FragU kh[2][4], kl[2][4];
#pragma unroll
        for (int ks = 0; ks < 2; ks++)
#pragma unroll
            for (int mt = 0; mt < 4; mt++) {
                kh[ks][mt].v = *(const short8v*)&KhS[((ks * 4 + mt) * 64) * 8 + lane8];
                kl[ks][mt].v = *(const short8v*)&KlS[((ks * 4 + mt) * 64) * 8 + lane8];
            }
        __syncthreads();   // all waves done reading K region
        if (jb < 31) {     // issue next K staging (lands during S/stats/P)
            gld_lds16(KhG + tbn + sl0 * 8, &KhS[sl0 * 8]);
            gld_lds16(KhG + tbn + sl1 * 8, &KhS[sl1 * 8]);
            gld_lds16(KlG + tbn + sl0 * 8, &KlS[sl0 * 8]);
            gld_lds16(KlG + tbn + sl1 * 8, &KlS[sl1 * 8]);
        }

        // ---- S^T = K @ Q^T (3 split passes) ----
        float4v st[4][2];
#pragma unroll
        for (int mt = 0; mt < 4; mt++)
#pragma unroll
            for (int rt = 0; rt < 2; rt++) st[mt][rt] = (float4v){0.f, 0.f, 0.f, 0.f};

#pragma unroll
        for (int ks = 0; ks < 2; ks++)
#pragma unroll
            for (int mt = 0; mt < 4; mt++)
#pragma unroll
                for (int rt = 0; rt < 2; rt++) {
                    st[mt][rt] = __builtin_amdgcn_mfma_f32_16x16x32_bf16(kh[ks][mt].v, Qh[rt][ks].v, st[mt][rt], 0, 0, 0);
                    st[mt][rt] = __builtin_amdgcn_mfma_f32_16x16x32_bf16(kh[ks][mt].v, Ql[rt][ks].v, st[mt][rt], 0, 0, 0);
                    st[mt][rt] = __builtin_amdgcn_mfma_f32_16x16x32_bf16(kl[ks][mt].v, Qh[rt][ks].v, st[mt][rt], 0, 0, 0);
                }

        // ---- stats (per-lane max + 2 shuffles, exp2, fp32 sum, rcp) ----
        float oscale[2];
#pragma unroll
        for (int rt = 0; rt < 2; rt++) {
            float v0 = fmaxf(fmaxf(st[0][rt][0], st[0][rt][1]), fmaxf(st[0][rt][2], st[0][rt][3]));
#pragma unroll
            for (int mt = 1; mt < 4; mt++) {
                float v1 = fmaxf(fmaxf(st[mt][rt][0], st[mt][rt][1]), fmaxf(st[mt][rt][2], st[mt][rt][3]));
                v0 = fmaxf(v0, v1);
            }
            v0 = fmaxf(v0, __shfl_xor(v0, 16, 64));
            v0 = fmaxf(v0, __shfl_xor(v0, 32, 64));
            const float mn = fmaxf(m_run[rt], v0);
            const float al = __builtin_amdgcn_exp2f(m_run[rt] - mn);

            float ssum = 0.f;
#pragma unroll
            for (int mt = 0; mt < 4; mt++)
#pragma unroll
                for (int r = 0; r < 4; r++) {
                    const float p = __builtin_amdgcn_exp2f(st[mt][rt][r] - mn);
                    st[mt][rt][r] = p;
                    ssum += p;
                }
            ssum += __shfl_xor(ssum, 16, 64);
            ssum += __shfl_xor(ssum, 32, 64);
            const float ln = al * l_run[rt] + ssum;
            const float inv = __builtin_amdgcn_rcpf(ln);
            oscale[rt] = al * inv;
#pragma unroll
            for (int mt = 0; mt < 4; mt++)
#pragma unroll
                for (int r = 0; r < 4; r++)
                    st[mt][rt][r] *= inv;
            m_run[rt] = mn;
            l_run[rt] = ln;
        }

        // ---- P'^T hi/lo -> wave-local LDS (B-frag layout, b64 writes) ----
#pragma unroll
        for (int rt = 0; rt < 2; rt++)
#pragma unroll
            for (int mt = 0; mt < 4; mt++) {
                unsigned u0 = __builtin_bit_cast(unsigned, st[mt][rt][0]);
                unsigned u1 = __builtin_bit_cast(unsigned, st[mt][rt][1]);
                unsigned u2 = __builtin_bit_cast(unsigned, st[mt][rt][2]);
                unsigned u3 = __builtin_bit_cast(unsigned, st[mt][rt][3]);
                unsigned h01 = (u0 >> 16) | (u1 & 0xffff0000u);
                unsigned h23 = (u2 >> 16) | (u3 & 0xffff0000u);
                float d0 = st[mt][rt][0] - __builtin_bit_cast(float, u0 & 0xffff0000u);
                float d1 = st[mt][rt][1] - __builtin_bit_cast(float, u1 & 0xffff0000u);
                float d2 = st[mt][rt][2] - __builtin_bit_cast(float, u2 & 0xffff0000u);
                float d3 = st[mt][rt][3] - __builtin_bit_cast(float, u3 & 0xffff0000u);
                unsigned l01 = (__builtin_bit_cast(unsigned, d0) >> 16) |
                               (__builtin_bit_cast(unsigned, d1) & 0xffff0000u);
                unsigned l23 = (__builtin_bit_cast(unsigned, d2) >> 16) |
                               (__builtin_bit_cast(unsigned, d3) & 0xffff0000u);
                const int idx = ((rt * 2 + (mt >> 1)) * 512 + (mt & 1) * 256) + pwq;
                *(uint2*)&ph[idx] = make_uint2(h01, h23);
                *(uint2*)&pl[idx] = make_uint2(l01, l23);
            }
        // wave-local: lgkmcnt orders write->read, no barrier

        // ---- reload P'^T as B-operand fragments ----
        FragU Ph[2][2], Pl[2][2];
#pragma unroll
        for (int rt = 0; rt < 2; rt++)
#pragma unroll
            for (int ks = 0; ks < 2; ks++) {
                Ph[rt][ks].v = *(const short8v*)&ph[((rt * 2 + ks) * 64) * 8 + lane8];
                Pl[rt][ks].v = *(const short8v*)&pl[((rt * 2 + ks) * 64) * 8 + lane8];
            }

        // ---- V frags -> regs (V region still valid) ----
        FragU vh[2][4], vl[2][4];
#pragma unroll
        for (int ks = 0; ks < 2; ks++)
#pragma unroll
            for (int dt = 0; dt < 4; dt++) {
                vh[ks][dt].v = *(const short8v*)&VhS[((ks * 4 + dt) * 64) * 8 + lane8];
                vl[ks][dt].v = *(const short8v*)&VlS[((ks * 4 + dt) * 64) * 8 + lane8];
            }
        __syncthreads();   // all waves done reading V region (K gld mostly landed)
        if (jb < 31) {     // issue next V staging (lands during PV MFMA)
            gld_lds16(VhG + tbn + sl0 * 8, &VhS[sl0 * 8]);
            gld_lds16(VhG + tbn + sl1 * 8, &VhS[sl1 * 8]);
            gld_lds16(VlG + tbn + sl0 * 8, &VlS[sl0 * 8]);
            gld_lds16(VlG + tbn + sl1 * 8, &VlS[sl1 * 8]);
        }

        // ---- O^T = oscale*O^T + V^T @ P'^T ----
#pragma unroll
        for (int dt = 0; dt < 4; dt++)
#pragma unroll
            for (int rt = 0; rt < 2; rt++)
#pragma unroll
                for (int r = 0; r < 4; r++)
                    Oacc[dt][rt][r] *= oscale[rt];

#pragma unroll
        for (int ks = 0; ks < 2; ks++)
#pragma unroll
            for (int dt = 0; dt < 4; dt++)
#pragma unroll
                for (int rt = 0; rt < 2; rt++) {
                    Oacc[dt][rt] = __builtin_amdgcn_mfma_f32_16x16x32_bf16(vh[ks][dt].v, Ph[rt][ks].v, Oacc[dt][rt], 0, 0, 0);
                    Oacc[dt][rt] = __builtin_amdgcn_mfma_f32_16x16x32_bf16(vl[ks][dt].v, Ph[rt][ks].v, Oacc[dt][rt], 0, 0, 0);
                    Oacc[dt][rt] = __builtin_amdgcn_mfma_f32_16x16x32_bf16(vh[ks][dt].v, Pl[rt][ks].v, Oacc[dt][rt], 0, 0, 0);
                }
    }

    // ---- epilogue: transpose O^T via wave-local LDS, split-bf16 coalesced store ----
    float* Pf = (float*)&PW[wave][0][0];
    const int q16 = lane >> 2, c = lane & 3;
#pragma unroll
    for (int rt = 0; rt < 2; rt++) {
#pragma unroll
        for (int dt = 0; dt < 4; dt++)
            *(float4v*)&Pf[l15 * 68 + dt * 16 + quad * 4] = Oacc[dt][rt];
        float vals[16];
#pragma unroll
        for (int kk = 0; kk < 4; kk++)
            *(float4v*)&vals[kk * 4] = *(const float4v*)&Pf[q16 * 68 + c * 16 + kk * 4];

        unsigned ho[8], lo8[8];
#pragma unroll
        for (int kk = 0; kk < 8; kk++) {
            unsigned short h0, l0, h1, l1;
            split_tr(vals[2 * kk], h0, l0);
            split_tr(vals[2 * kk + 1], h1, l1);
            ho[kk]  = (unsigned)h0 | ((unsigned)h1 << 16);
            lo8[kk] = (unsigned)l0 | ((unsigned)l1 << 16);
        }
        const int qrow = qs0 + rt * 16 + q16;
        const size_t off = (size_t)(b * SS + qrow) * DIM + h * HD + c * 16;
        *(uint4*)&Oh[off]     = make_uint4(ho[0], ho[1], ho[2], ho[3]);
        *(uint4*)&Oh[off + 8] = make_uint4(ho[4], ho[5], ho[6], ho[7]);
        *(uint4*)&Ol[off]     = make_uint4(lo8[0], lo8[1], lo8[2], lo8[3]);
        *(uint4*)&Ol[off + 8] = make_uint4(lo8[4], lo8[5], lo8[6], lo8[7]);
    }
}

// ---------------------------------------------------------------------------
extern "C" void kernel_launch(void* const* d_in, const int* in_sizes, int n_in,
                              void* d_out, int out_size, void* d_ws, size_t ws_size,
                              hipStream_t stream)
{
    const float* x  = (const float*)d_in[0];
    const float* Wq = (const float*)d_in[1];
    const float* Wk = (const float*)d_in[2];
    const float* Wv = (const float*)d_in[3];
    const float* Wo = (const float*)d_in[4];
    float* out = (float*)d_out;

    char* w = (char*)d_ws;
    float*   qw  = (float*)(w);                        // 16 MB
    ushortT* OhS = (ushortT*)(w + ((size_t)16 << 20)); // 8 MB (attn output hi)
    ushortT* OlS = (ushortT*)(w + ((size_t)24 << 20)); // 8 MB (attn output lo)
    ushortT* VhG = (ushortT*)(w + ((size_t)32 << 20)); // 8 MB (V frag tiles)
    ushortT* VlG = (ushortT*)(w + ((size_t)40 << 20)); // 8 MB
    ushortT* XhS = (ushortT*)(w + ((size_t)48 << 20)); // 8 MB
    ushortT* XlS = (ushortT*)(w + ((size_t)56 << 20)); // 8 MB
    ushortT* WtH = (ushortT*)(w + ((size_t)64 << 20)); // 8 MB (4 matrices)
    ushortT* WtL = (ushortT*)(w + ((size_t)72 << 20)); // 8 MB
    ushortT* KhG = (ushortT*)(w + ((size_t)80 << 20)); // 8 MB (K frag tiles)
    ushortT* KlG = (ushortT*)(w + ((size_t)88 << 20)); // 8 MB  -> 96 MB total

    dim3 blk(256);

    // X split + W transpose/split, one launch
    prep_kernel<<<dim3(16, 16, 20), blk, 0, stream>>>(
        x, Wq, Wk, Wv, Wo, XhS, XlS, WtH, WtL);

    // Q/K/V projections; z==1 emits K frag tiles, z==2 emits V frag tiles
    gemm_bt_split_kernel<<<dim3(8, 32, 3), blk, 0, stream>>>(
        XhS, XlS, WtH, WtL, qw, KhG, KlG, VhG, VlG);

    // attention (exact reference recurrence, kv block = 64, pipelined staging)
    attn_mfma_kernel<<<dim3(16, 32), blk, 0, stream>>>(qw, KhG, KlG, VhG, VlG, OhS, OlS);

    // output projection (z==0 path, fp32 out)
    gemm_bt_split_kernel<<<dim3(8, 32, 1), blk, 0, stream>>>(
        OhS, OlS, WtH + (size_t)3 * 1024 * 1024, WtL + (size_t)3 * 1024 * 1024,
        out, nullptr, nullptr, nullptr, nullptr);
}

// Round 9
// 332.297 us; speedup vs baseline: 2.3493x; 2.3493x over previous
//
#include <hip/hip_runtime.h>
#include <hip/hip_bf16.h>
#include <math.h>

#define BB   2
#define SS   2048
#define DIM  1024
#define NH   16
#define HD   64
#define MTOT (BB * SS)   // 4096

typedef unsigned short ushortT;
typedef __attribute__((ext_vector_type(8))) short short8v;   // 8 bf16 (4 VGPRs)
typedef __attribute__((ext_vector_type(4))) float float4v;   // 4 fp32 acc

union FragU { short8v v; unsigned short us[8]; unsigned int u[4]; };

__device__ inline unsigned short f2bf(float x) {             // fp32 -> bf16 RNE
    unsigned u = __builtin_bit_cast(unsigned, x);
    u += 0x7fffu + ((u >> 16) & 1u);
    return (unsigned short)(u >> 16);
}
__device__ inline float bf2f(unsigned short h) {
    unsigned u = ((unsigned)h) << 16;
    return __builtin_bit_cast(float, u);
}
// truncation split: hi = trunc-to-bf16(x), lo = trunc-to-bf16(x - hi)
__device__ inline void split_tr(float x, unsigned short& hi, unsigned short& lo) {
    unsigned u = __builtin_bit_cast(unsigned, x);
    hi = (unsigned short)(u >> 16);
    float hf = __builtin_bit_cast(float, u & 0xffff0000u);
    lo = (unsigned short)(__builtin_bit_cast(unsigned, x - hf) >> 16);
}
__device__ inline void split4(const float4& x, short4& hi, short4& lo) {
    unsigned short h0 = f2bf(x.x), h1 = f2bf(x.y), h2 = f2bf(x.z), h3 = f2bf(x.w);
    hi = make_short4((short)h0, (short)h1, (short)h2, (short)h3);
    lo = make_short4((short)f2bf(x.x - bf2f(h0)), (short)f2bf(x.y - bf2f(h1)),
                     (short)f2bf(x.z - bf2f(h2)), (short)f2bf(x.w - bf2f(h3)));
}
// async global->LDS, 16 B per lane (dest = wave-uniform base + lane*16)
__device__ inline void gld_lds16(const void* g, void* l) {
    __builtin_amdgcn_global_load_lds(
        (const __attribute__((address_space(1))) void*)g,
        (__attribute__((address_space(3))) void*)l, 16, 0, 0);
}

// ---------------------------------------------------------------------------
// fp32 -> bf16 hi/lo elementwise split (X)
// ---------------------------------------------------------------------------
__global__ __launch_bounds__(256) void convert_split_kernel(
    const float* __restrict__ in, ushortT* __restrict__ hi, ushortT* __restrict__ lo, int n4)
{
    int t = blockIdx.x * 256 + threadIdx.x;
    if (t < n4) {
        float4 x = ((const float4*)in)[t];
        short4 h, l; split4(x, h, l);
        ((short4*)hi)[t] = h;
        ((short4*)lo)[t] = l;
    }
}

// ---------------------------------------------------------------------------
// W (1024x1024 fp32, K-major) -> W^T (bf16 hi/lo, N-major rows of K)
// ---------------------------------------------------------------------------
__global__ __launch_bounds__(256) void transpose_split_kernel(
    const float* __restrict__ W0, const float* __restrict__ W1,
    const float* __restrict__ W2, const float* __restrict__ W3,
    ushortT* __restrict__ WtH, ushortT* __restrict__ WtL)
{
    const int z = blockIdx.z;
    const float* __restrict__ W = (z == 0) ? W0 : (z == 1) ? W1 : (z == 2) ? W2 : W3;
    ushortT* H = WtH + (size_t)z * 1024 * 1024;
    ushortT* L = WtL + (size_t)z * 1024 * 1024;

    __shared__ float T[64][65];
    const int k0 = blockIdx.y * 64, n0 = blockIdx.x * 64;
    const int tid = threadIdx.x;
    const int c4 = (tid & 15) * 4;

#pragma unroll
    for (int i = 0; i < 4; i++) {
        int r = (tid >> 4) + 16 * i;
        *(float4*)&T[r][c4] = *(const float4*)(W + (size_t)(k0 + r) * 1024 + n0 + c4);
    }
    __syncthreads();
#pragma unroll
    for (int i = 0; i < 4; i++) {
        int n = (tid >> 4) + 16 * i;
        float4 vv = make_float4(T[c4 + 0][n], T[c4 + 1][n], T[c4 + 2][n], T[c4 + 3][n]);
        short4 h, l; split4(vv, h, l);
        *(short4*)&H[(size_t)(n0 + n) * 1024 + k0 + c4] = h;
        *(short4*)&L[(size_t)(n0 + n) * 1024 + k0 + c4] = l;
    }
}

// ---------------------------------------------------------------------------
// K fp32 (B,S,H*D) -> bf16 hi/lo 64x64 tiles, frag-major [frag8][lane64][j8].
// K frag f=ks*4+t: element (kv=t*16+l15, d=ks*32+quad*8+j)   (A-op for S^T)
// ---------------------------------------------------------------------------
__global__ __launch_bounds__(256) void kv_convert_kernel(
    const float* __restrict__ kw,
    ushortT* __restrict__ KhG, ushortT* __restrict__ KlG)
{
    const int jb = blockIdx.x, bh = blockIdx.y;
    const int b = bh >> 4, h = bh & 15;

    __shared__ float T[64][68];
    const int tid = threadIdx.x;
    const size_t ibase = (size_t)b * SS * DIM + (size_t)h * HD + (size_t)(jb * 64) * DIM;
    const int c4 = (tid & 15) * 4;
#pragma unroll
    for (int i = 0; i < 4; i++) {
        int r = (tid >> 4) + 16 * i;
        *(float4*)&T[r][c4] = *(const float4*)(kw + ibase + (size_t)r * DIM + c4);
    }
    __syncthreads();

    ushortT* oh = KhG + (size_t)(bh * 32 + jb) * 4096;
    ushortT* ol = KlG + (size_t)(bh * 32 + jb) * 4096;

#pragma unroll
    for (int i = 0; i < 2; i++) {
        const int s = tid + i * 256;          // slot 0..511
        const int f = s >> 6;                 // frag 0..7
        const int lane = s & 63;
        const int ks = f >> 2, c = f & 3;
        const int qd = lane >> 4, l15 = lane & 15;
        const int kv = c * 16 + l15;
        const int d0 = ks * 32 + qd * 8;
        ushortT hv[8], lv[8];
#pragma unroll
        for (int j = 0; j < 8; j++) split_tr(T[kv][d0 + j], hv[j], lv[j]);
        *(short4*)&oh[s * 8]     = *(short4*)&hv[0];
        *(short4*)&oh[s * 8 + 4] = *(short4*)&hv[4];
        *(short4*)&ol[s * 8]     = *(short4*)&lv[0];
        *(short4*)&ol[s * 8 + 4] = *(short4*)&lv[4];
    }
}

// ---------------------------------------------------------------------------
// Split-bf16 MFMA GEMM. z==2 (V projection) stores its output DIRECTLY as
// split-bf16 frag-major attention tiles. z==0/1 store fp32 rows.
// launch_bounds (256,2): 2 blocks/CU — (256,3) cost ~18 µs via L2 pressure
// (round 4->5 non-attn delta attribution); reverted.
// ---------------------------------------------------------------------------
__global__ __launch_bounds__(256, 2) void gemm_bt_split_kernel(
    const ushortT* __restrict__ Ah, const ushortT* __restrict__ Al,
    const ushortT* __restrict__ BtH, const ushortT* __restrict__ BtL,
    float* __restrict__ Y0, float* __restrict__ Y1,
    ushortT* __restrict__ VhG, ushortT* __restrict__ VlG)
{
    const int z = blockIdx.z;
    const ushortT* __restrict__ Bh = BtH + (size_t)z * 1024 * 1024;
    const ushortT* __restrict__ Bl = BtL + (size_t)z * 1024 * 1024;

    const int K = 1024, N = 1024;
    const int m0 = blockIdx.y * 128;
    const int n0 = blockIdx.x * 128;

    __shared__ __align__(16) ushortT AhS[128 * 32];
    __shared__ __align__(16) ushortT AlS[128 * 32];
    __shared__ __align__(16) ushortT BhS[128 * 32];
    __shared__ __align__(16) ushortT BlS[128 * 32];

    const int tid  = threadIdx.x;
    const int wave = tid >> 6, lane = tid & 63;
    const int quad = lane >> 4, l15 = lane & 15;
    const int wm = wave >> 1, wn = wave & 1;

    const int s0 = tid, s1 = tid + 256;
    const int ar0 = s0 >> 2, ak0 = (s0 & 3) * 8;
    const int ar1 = s1 >> 2, ak1 = (s1 & 3) * 8;

    float4v acc[4][4];
#pragma unroll
    for (int i = 0; i < 4; i++)
#pragma unroll
        for (int j = 0; j < 4; j++) acc[i][j] = (float4v){0.f, 0.f, 0.f, 0.f};

    for (int k0 = 0; k0 < K; k0 += 32) {
        __syncthreads();
        gld_lds16(Ah + (size_t)(m0 + ar0) * K + k0 + ak0, &AhS[s0 * 8]);
        gld_lds16(Ah + (size_t)(m0 + ar1) * K + k0 + ak1, &AhS[s1 * 8]);
        gld_lds16(Al + (size_t)(m0 + ar0) * K + k0 + ak0, &AlS[s0 * 8]);
        gld_lds16(Al + (size_t)(m0 + ar1) * K + k0 + ak1, &AlS[s1 * 8]);
        gld_lds16(Bh + (size_t)(n0 + ar0) * K + k0 + ak0, &BhS[s0 * 8]);
        gld_lds16(Bh + (size_t)(n0 + ar1) * K + k0 + ak1, &BhS[s1 * 8]);
        gld_lds16(Bl + (size_t)(n0 + ar0) * K + k0 + ak0, &BlS[s0 * 8]);
        gld_lds16(Bl + (size_t)(n0 + ar1) * K + k0 + ak1, &BlS[s1 * 8]);
        __syncthreads();

        FragU ah[4], al[4], bh[4], bl[4];
#pragma unroll
        for (int t = 0; t < 4; t++) {
            ah[t].v = *(const short8v*)&AhS[(wm * 64 + t * 16 + l15) * 32 + quad * 8];
            al[t].v = *(const short8v*)&AlS[(wm * 64 + t * 16 + l15) * 32 + quad * 8];
            bh[t].v = *(const short8v*)&BhS[(wn * 64 + t * 16 + l15) * 32 + quad * 8];
            bl[t].v = *(const short8v*)&BlS[(wn * 64 + t * 16 + l15) * 32 + quad * 8];
        }
#pragma unroll
        for (int mt = 0; mt < 4; mt++)
#pragma unroll
            for (int nt = 0; nt < 4; nt++) {
                acc[mt][nt] = __builtin_amdgcn_mfma_f32_16x16x32_bf16(ah[mt].v, bh[nt].v, acc[mt][nt], 0, 0, 0);
                acc[mt][nt] = __builtin_amdgcn_mfma_f32_16x16x32_bf16(ah[mt].v, bl[nt].v, acc[mt][nt], 0, 0, 0);
                acc[mt][nt] = __builtin_amdgcn_mfma_f32_16x16x32_bf16(al[mt].v, bh[nt].v, acc[mt][nt], 0, 0, 0);
            }
    }

    if (z == 2) {
        // ---- V epilogue: direct frag-major split-bf16 tile store ----
        const int b  = m0 >> 11;
        const int jb = ((m0 & 2047) >> 6) + wm;
        const int h  = (n0 >> 6) + wn;
        const size_t tb = (size_t)((b * 16 + h) * 32 + jb) * 4096;
        ushortT* vh = VhG + tb;
        ushortT* vl = VlG + tb;
#pragma unroll
        for (int mt = 0; mt < 4; mt++)
#pragma unroll
            for (int nt = 0; nt < 4; nt++) {
                // frag f = (mt>>1)*4 + nt ; lane_a = ((mt&1)*2+(quad>>1))*16 + l15 ;
                // j = (quad&1)*4 + r  -> r-consecutive
                const int off = ((((mt >> 1) * 4 + nt) * 64 +
                                  ((mt & 1) * 2 + (quad >> 1)) * 16 + l15) * 8) +
                                (quad & 1) * 4;
                float4 vv = make_float4(acc[mt][nt][0], acc[mt][nt][1],
                                        acc[mt][nt][2], acc[mt][nt][3]);
                unsigned short h0, l0, h1, l1, h2, l2, h3, l3;
                split_tr(vv.x, h0, l0); split_tr(vv.y, h1, l1);
                split_tr(vv.z, h2, l2); split_tr(vv.w, h3, l3);
                *(short4*)&vh[off] = make_short4((short)h0, (short)h1, (short)h2, (short)h3);
                *(short4*)&vl[off] = make_short4((short)l0, (short)l1, (short)l2, (short)l3);
            }
    } else {
        float* __restrict__ Y = (z == 0) ? Y0 : Y1;
#pragma unroll
        for (int mt = 0; mt < 4; mt++)
#pragma unroll
            for (int r = 0; r < 4; r++) {
                const int row = m0 + wm * 64 + mt * 16 + quad * 4 + r;
                float* yp = Y + (size_t)row * N + n0 + wn * 64 + l15;
#pragma unroll
                for (int nt = 0; nt < 4; nt++)
                    yp[nt * 16] = acc[mt][nt][r];
            }
    }
}

// ---------------------------------------------------------------------------
// MFMA attention (round-7 kernel, measured 127 us): S^T = K·Q^T orientation,
// LDS-staged K/V frag tiles (shared by 4 waves), per-lane stats (2 shuffles),
// exp2 softmax, wave-local P round-trip, split-bf16 O output.
// Exact reference recurrence: O = (alpha*O + P@V)/l_new EVERY kv step.
// ---------------------------------------------------------------------------
__global__ __launch_bounds__(256, 2) void attn_mfma_kernel(
    const float* __restrict__ q,
    const ushortT* __restrict__ KhG, const ushortT* __restrict__ KlG,
    const ushortT* __restrict__ VhG, const ushortT* __restrict__ VlG,
    ushortT* __restrict__ Oh, ushortT* __restrict__ Ol)
{
    __shared__ __align__(16) ushortT KhS[4096];
    __shared__ __align__(16) ushortT KlS[4096];
    __shared__ __align__(16) ushortT VhS[4096];
    __shared__ __align__(16) ushortT VlS[4096];
    __shared__ __align__(16) ushortT PW[4][2][2048];   // [wave][hi/lo][frag4*slot64*j8]

    const int tid  = threadIdx.x;
    const int wave = tid >> 6, lane = tid & 63;
    const int quad = lane >> 4, l15 = lane & 15;
    const int bh = blockIdx.y, b = bh >> 4, h = bh & 15;
    const size_t base = (size_t)b * SS * DIM + (size_t)h * HD;
    const int qs0 = blockIdx.x * 128 + wave * 32;

    // ---- Q fragments: scale = 1/8 * log2(e) folded in (exp2 domain) ----
    const float qscale = 0.125f * 1.4426950408889634f;
    FragU Qh[2][2], Ql[2][2];
#pragma unroll
    for (int rt = 0; rt < 2; rt++) {
        const int qrow = qs0 + rt * 16 + l15;
#pragma unroll
        for (int ks = 0; ks < 2; ks++) {
            const float* p0 = q + base + (size_t)qrow * DIM + ks * 32 + quad * 8;
            float4 a = *(const float4*)(p0);
            float4 c = *(const float4*)(p0 + 4);
            float e[8] = {a.x, a.y, a.z, a.w, c.x, c.y, c.z, c.w};
#pragma unroll
            for (int j = 0; j < 8; j++) {
                float x = e[j] * qscale;
                unsigned short hs = f2bf(x);
                Qh[rt][ks].us[j] = hs;
                Ql[rt][ks].us[j] = f2bf(x - bf2f(hs));
            }
        }
    }

    float4v Oacc[4][2];   // [dt][rt], O^T: row d=dt*16+quad*4+r, col q=rt*16+l15
#pragma unroll
    for (int dt = 0; dt < 4; dt++)
#pragma unroll
        for (int rt = 0; rt < 2; rt++) Oacc[dt][rt] = (float4v){0.f, 0.f, 0.f, 0.f};

    float m_run[2] = {-INFINITY, -INFINITY};
    float l_run[2] = {0.f, 0.f};

    const int sl0 = wave * 128 + lane, sl1 = sl0 + 64;
    ushortT* ph = &PW[wave][0][0];
    ushortT* pl = &PW[wave][1][0];
    const int pwq = ((quad >> 1) * 16 + l15) * 8 + (quad & 1) * 4;
    const int lane8 = lane * 8;

    for (int jb = 0; jb < 32; jb++) {
        __syncthreads();   // prev-iter K/V readers done
        {
            const size_t tb = (size_t)(bh * 32 + jb) * 4096;
            gld_lds16(KhG + tb + sl0 * 8, &KhS[sl0 * 8]);
            gld_lds16(KhG + tb + sl1 * 8, &KhS[sl1 * 8]);
            gld_lds16(KlG + tb + sl0 * 8, &KlS[sl0 * 8]);
            gld_lds16(KlG + tb + sl1 * 8, &KlS[sl1 * 8]);
            gld_lds16(VhG + tb + sl0 * 8, &VhS[sl0 * 8]);
            gld_lds16(VhG + tb + sl1 * 8, &VhS[sl1 * 8]);
            gld_lds16(VlG + tb + sl0 * 8, &VlS[sl0 * 8]);
            gld_lds16(VlG + tb + sl1 * 8, &VlS[sl1 * 8]);
        }
        __syncthreads();   // drains vmcnt before use

        // ---- S^T = K @ Q^T (3 split passes); C: row=kv=mt*16+quad*4+r, col=q=l15 ----
        float4v st[4][2];
#pragma unroll
        for (int mt = 0; mt < 4; mt++)
#pragma unroll
            for (int rt = 0; rt < 2; rt++) st[mt][rt] = (float4v){0.f, 0.f, 0.f, 0.f};

#pragma unroll
        for (int ks = 0; ks < 2; ks++) {
            FragU kh[4], kl[4];
#pragma unroll
            for (int mt = 0; mt < 4; mt++) {
                kh[mt].v = *(const short8v*)&KhS[((ks * 4 + mt) * 64) * 8 + lane8];
                kl[mt].v = *(const short8v*)&KlS[((ks * 4 + mt) * 64) * 8 + lane8];
            }
#pragma unroll
            for (int mt = 0; mt < 4; mt++)
#pragma unroll
                for (int rt = 0; rt < 2; rt++) {
                    st[mt][rt] = __builtin_amdgcn_mfma_f32_16x16x32_bf16(kh[mt].v, Qh[rt][ks].v, st[mt][rt], 0, 0, 0);
                    st[mt][rt] = __builtin_amdgcn_mfma_f32_16x16x32_bf16(kh[mt].v, Ql[rt][ks].v, st[mt][rt], 0, 0, 0);
                    st[mt][rt] = __builtin_amdgcn_mfma_f32_16x16x32_bf16(kl[mt].v, Qh[rt][ks].v, st[mt][rt], 0, 0, 0);
                }
        }

        // ---- stats: per-lane max (16 vals) + 2 shuffles; exp2; fp32 VALU sum ----
        float oscale[2];
#pragma unroll
        for (int rt = 0; rt < 2; rt++) {
            float v0 = fmaxf(fmaxf(st[0][rt][0], st[0][rt][1]), fmaxf(st[0][rt][2], st[0][rt][3]));
#pragma unroll
            for (int mt = 1; mt < 4; mt++) {
                float v1 = fmaxf(fmaxf(st[mt][rt][0], st[mt][rt][1]), fmaxf(st[mt][rt][2], st[mt][rt][3]));
                v0 = fmaxf(v0, v1);
            }
            v0 = fmaxf(v0, __shfl_xor(v0, 16, 64));
            v0 = fmaxf(v0, __shfl_xor(v0, 32, 64));
            const float mn = fmaxf(m_run[rt], v0);
            const float al = __builtin_amdgcn_exp2f(m_run[rt] - mn);   // 0 on first iter

            float ssum = 0.f;
#pragma unroll
            for (int mt = 0; mt < 4; mt++)
#pragma unroll
                for (int r = 0; r < 4; r++) {
                    const float p = __builtin_amdgcn_exp2f(st[mt][rt][r] - mn);
                    st[mt][rt][r] = p;
                    ssum += p;
                }
            ssum += __shfl_xor(ssum, 16, 64);
            ssum += __shfl_xor(ssum, 32, 64);
            const float ln = al * l_run[rt] + ssum;
            const float inv = __builtin_amdgcn_rcpf(ln);
            oscale[rt] = al * inv;
            // scale P by inv pre-split (fold the per-step division into P)
#pragma unroll
            for (int mt = 0; mt < 4; mt++)
#pragma unroll
                for (int r = 0; r < 4; r++)
                    st[mt][rt][r] *= inv;
            m_run[rt] = mn;
            l_run[rt] = ln;
        }

        // ---- write P'^T hi/lo as b64 into B-frag layout (wave-local LDS) ----
#pragma unroll
        for (int rt = 0; rt < 2; rt++)
#pragma unroll
            for (int mt = 0; mt < 4; mt++) {
                unsigned u0 = __builtin_bit_cast(unsigned, st[mt][rt][0]);
                unsigned u1 = __builtin_bit_cast(unsigned, st[mt][rt][1]);
                unsigned u2 = __builtin_bit_cast(unsigned, st[mt][rt][2]);
                unsigned u3 = __builtin_bit_cast(unsigned, st[mt][rt][3]);
                unsigned h01 = (u0 >> 16) | (u1 & 0xffff0000u);
                unsigned h23 = (u2 >> 16) | (u3 & 0xffff0000u);
                float d0 = st[mt][rt][0] - __builtin_bit_cast(float, u0 & 0xffff0000u);
                float d1 = st[mt][rt][1] - __builtin_bit_cast(float, u1 & 0xffff0000u);
                float d2 = st[mt][rt][2] - __builtin_bit_cast(float, u2 & 0xffff0000u);
                float d3 = st[mt][rt][3] - __builtin_bit_cast(float, u3 & 0xffff0000u);
                unsigned l01 = (__builtin_bit_cast(unsigned, d0) >> 16) |
                               (__builtin_bit_cast(unsigned, d1) & 0xffff0000u);
                unsigned l23 = (__builtin_bit_cast(unsigned, d2) >> 16) |
                               (__builtin_bit_cast(unsigned, d3) & 0xffff0000u);
                const int idx = ((rt * 2 + (mt >> 1)) * 512 + (mt & 1) * 256) + pwq;
                *(uint2*)&ph[idx] = make_uint2(h01, h23);
                *(uint2*)&pl[idx] = make_uint2(l01, l23);
            }
        // wave-local region: lgkmcnt orders write->read, no barrier

        // ---- reload P'^T as B-operand fragments (linear b128) ----
        FragU Ph[2][2], Pl[2][2];
#pragma unroll
        for (int rt = 0; rt < 2; rt++)
#pragma unroll
            for (int ks = 0; ks < 2; ks++) {
                Ph[rt][ks].v = *(const short8v*)&ph[((rt * 2 + ks) * 64) * 8 + lane8];
                Pl[rt][ks].v = *(const short8v*)&pl[((rt * 2 + ks) * 64) * 8 + lane8];
            }

        // ---- O^T = oscale*O^T + V^T @ P'^T ----
#pragma unroll
        for (int dt = 0; dt < 4; dt++)
#pragma unroll
            for (int rt = 0; rt < 2; rt++)
#pragma unroll
                for (int r = 0; r < 4; r++)
                    Oacc[dt][rt][r] *= oscale[rt];

#pragma unroll
        for (int ks = 0; ks < 2; ks++)
#pragma unroll
            for (int dt = 0; dt < 4; dt++) {
                FragU vh, vl;
                vh.v = *(const short8v*)&VhS[((ks * 4 + dt) * 64) * 8 + lane8];
                vl.v = *(const short8v*)&VlS[((ks * 4 + dt) * 64) * 8 + lane8];
#pragma unroll
                for (int rt = 0; rt < 2; rt++) {
                    Oacc[dt][rt] = __builtin_amdgcn_mfma_f32_16x16x32_bf16(vh.v, Ph[rt][ks].v, Oacc[dt][rt], 0, 0, 0);
                    Oacc[dt][rt] = __builtin_amdgcn_mfma_f32_16x16x32_bf16(vl.v, Ph[rt][ks].v, Oacc[dt][rt], 0, 0, 0);
                    Oacc[dt][rt] = __builtin_amdgcn_mfma_f32_16x16x32_bf16(vh.v, Pl[rt][ks].v, Oacc[dt][rt], 0, 0, 0);
                }
            }
    }

    // ---- epilogue: transpose O^T via wave-local LDS, split-bf16 coalesced store ----
    float* Pf = (float*)&PW[wave][0][0];
    const int q16 = lane >> 2, c = lane & 3;
#pragma unroll
    for (int rt = 0; rt < 2; rt++) {
#pragma unroll
        for (int dt = 0; dt < 4; dt++)
            *(float4v*)&Pf[l15 * 68 + dt * 16 + quad * 4] = Oacc[dt][rt];
        float vals[16];
#pragma unroll
        for (int kk = 0; kk < 4; kk++)
            *(float4v*)&vals[kk * 4] = *(const float4v*)&Pf[q16 * 68 + c * 16 + kk * 4];

        unsigned ho[8], lo8[8];
#pragma unroll
        for (int kk = 0; kk < 8; kk++) {
            unsigned short h0, l0, h1, l1;
            split_tr(vals[2 * kk], h0, l0);
            split_tr(vals[2 * kk + 1], h1, l1);
            ho[kk]  = (unsigned)h0 | ((unsigned)h1 << 16);
            lo8[kk] = (unsigned)l0 | ((unsigned)l1 << 16);
        }
        const int qrow = qs0 + rt * 16 + q16;
        const size_t off = (size_t)(b * SS + qrow) * DIM + h * HD + c * 16;
        *(uint4*)&Oh[off]     = make_uint4(ho[0], ho[1], ho[2], ho[3]);
        *(uint4*)&Oh[off + 8] = make_uint4(ho[4], ho[5], ho[6], ho[7]);
        *(uint4*)&Ol[off]     = make_uint4(lo8[0], lo8[1], lo8[2], lo8[3]);
        *(uint4*)&Ol[off + 8] = make_uint4(lo8[4], lo8[5], lo8[6], lo8[7]);
    }
}

// ---------------------------------------------------------------------------
extern "C" void kernel_launch(void* const* d_in, const int* in_sizes, int n_in,
                              void* d_out, int out_size, void* d_ws, size_t ws_size,
                              hipStream_t stream)
{
    const float* x  = (const float*)d_in[0];
    const float* Wq = (const float*)d_in[1];
    const float* Wk = (const float*)d_in[2];
    const float* Wv = (const float*)d_in[3];
    const float* Wo = (const float*)d_in[4];
    float* out = (float*)d_out;

    char* w = (char*)d_ws;
    float*   qw  = (float*)(w);                        // 16 MB
    float*   kw  = (float*)(w + ((size_t)16 << 20));   // 16 MB (later Oh/Ol)
    ushortT* VhG = (ushortT*)(w + ((size_t)32 << 20)); // 8 MB (V frag tiles, from GEMM)
    ushortT* VlG = (ushortT*)(w + ((size_t)40 << 20)); // 8 MB
    ushortT* XhS = (ushortT*)(w + ((size_t)48 << 20)); // 8 MB
    ushortT* XlS = (ushortT*)(w + ((size_t)56 << 20)); // 8 MB
    ushortT* WtH = (ushortT*)(w + ((size_t)64 << 20)); // 8 MB (4 matrices)
    ushortT* WtL = (ushortT*)(w + ((size_t)72 << 20)); // 8 MB
    ushortT* KhG = (ushortT*)(w + ((size_t)80 << 20)); // 8 MB
    ushortT* KlG = (ushortT*)(w + ((size_t)88 << 20)); // 8 MB  -> 96 MB total
    ushortT* OhS = (ushortT*)kw;                       // reuse after kv_convert
    ushortT* OlS = (ushortT*)(w + ((size_t)24 << 20));

    dim3 blk(256);
    const int n4 = MTOT * DIM / 4;

    // split X -> bf16 hi/lo; transpose+split all four W
    convert_split_kernel<<<dim3(n4 / 256), blk, 0, stream>>>(x, XhS, XlS, n4);
    transpose_split_kernel<<<dim3(16, 16, 4), blk, 0, stream>>>(Wq, Wk, Wv, Wo, WtH, WtL);

    // Q/K/V projections; z==2 (V) emits frag-major split tiles directly
    gemm_bt_split_kernel<<<dim3(8, 32, 3), blk, 0, stream>>>(
        XhS, XlS, WtH, WtL, qw, kw, VhG, VlG);

    // K -> frag-major split tiles
    kv_convert_kernel<<<dim3(32, 32), blk, 0, stream>>>(kw, KhG, KlG);

    // attention (exact reference recurrence, kv block = 64)
    attn_mfma_kernel<<<dim3(16, 32), blk, 0, stream>>>(qw, KhG, KlG, VhG, VlG, OhS, OlS);

    // output projection (z=0 path, fp32 out)
    gemm_bt_split_kernel<<<dim3(8, 32, 1), blk, 0, stream>>>(
        OhS, OlS, WtH + (size_t)3 * 1024 * 1024, WtL + (size_t)3 * 1024 * 1024,
        out, nullptr, nullptr, nullptr);
}